// Round 15
// baseline (179.330 us; speedup 1.0000x reference)
//
#include <hip/hip_runtime.h>

typedef __attribute__((ext_vector_type(8))) short bf16x8;   // MFMA A/B frag (8 bf16)
typedef __attribute__((ext_vector_type(4))) float f32x4;    // MFMA C/D frag
typedef __attribute__((ext_vector_type(8))) unsigned short u16x8;
typedef __attribute__((ext_vector_type(4))) unsigned short u16x4;
typedef __attribute__((ext_vector_type(2))) unsigned u32x2;

__device__ __forceinline__ unsigned short f2bf(float f) {
  unsigned u = __builtin_bit_cast(unsigned, f);
  return (unsigned short)((u + 0x7fffu + ((u >> 16) & 1u)) >> 16);
}

__device__ __forceinline__ unsigned cvt_pk_bf16(float lo, float hi) {
  unsigned r;
  asm("v_cvt_pk_bf16_f32 %0, %1, %2" : "=v"(r) : "v"(lo), "v"(hi));
  return r;
}

__device__ __forceinline__ void gl_lds16(const void* g, void* l) {
  __builtin_amdgcn_global_load_lds((const __attribute__((address_space(1))) unsigned*)g,
                                   (__attribute__((address_space(3))) unsigned*)l, 16, 0, 0);
}

// ---------------- merged prep: x->bf16 convert + both weight transposes ----------------
__global__ __launch_bounds__(256) void k_prep(const float* __restrict__ x,
                                              unsigned short* __restrict__ xb,
                                              const float* __restrict__ wq,
                                              unsigned short* __restrict__ wqT,
                                              const float* __restrict__ wp,
                                              unsigned short* __restrict__ wpT) {
  __shared__ float tile[32][33];
  const int bx = blockIdx.x;
  const int t = threadIdx.x;
  if (bx < 4096) {  // convert x fp32 -> bf16, 8 elems/thread
    const int i = bx * 256 + t;
    const float4* s = (const float4*)x;
    float4 a = s[2 * i], b = s[2 * i + 1];
    u16x8 o;
    o[0] = f2bf(a.x); o[1] = f2bf(a.y); o[2] = f2bf(a.z); o[3] = f2bf(a.w);
    o[4] = f2bf(b.x); o[5] = f2bf(b.y); o[6] = f2bf(b.z); o[7] = f2bf(b.w);
    *(u16x8*)(xb + 8 * (size_t)i) = o;
    return;
  }
  // weight transpose+convert [K][N] f32 -> [N][K] bf16
  const int b = bx - 4096;
  const float* w;
  unsigned short* wT;
  int Nn, bb;
  if (b < 3072) { w = wq; wT = wqT; Nn = 3072; bb = b; }
  else          { w = wp; wT = wpT; Nn = 1024; bb = b - 3072; }
  const int k0 = (bb & 31) * 32, n0 = (bb >> 5) * 32;
  const int i = t >> 3, j = (t & 7) * 4;
  float4 v = *(const float4*)(w + (size_t)(k0 + i) * Nn + n0 + j);
  tile[i][j] = v.x; tile[i][j + 1] = v.y; tile[i][j + 2] = v.z; tile[i][j + 3] = v.w;
  __syncthreads();
  const int n = i, k4 = j;
  u16x4 o;
  o[0] = f2bf(tile[k4 + 0][n]); o[1] = f2bf(tile[k4 + 1][n]);
  o[2] = f2bf(tile[k4 + 2][n]); o[3] = f2bf(tile[k4 + 3][n]);
  *(u16x4*)(wT + (size_t)(n0 + n) * 1024 + k0 + k4) = o;
}

// ---------------- GEMM: C[M,Nx] = A[M,1024] @ Bt[Nx,1024]^T + bias ----------------
// 128x128 tile, BK=32, 3-slot LDS ring, counted vmcnt(4), row-XOR swizzle,
// XCD band map (each XCD owns an 8-M-tile band x all N).  (Round-12 verified.)
// EPI 0: fp32 row-major out.  EPI 1: scatter to Q/K bf16 (scaled) + V transposed.
template <int EPI>
__global__ __launch_bounds__(256) void k_gemm(const unsigned short* __restrict__ A,
                                              const unsigned short* __restrict__ Bt,
                                              const float* __restrict__ bias, int Nx,
                                              float* __restrict__ outF,
                                              unsigned short* __restrict__ Qb,
                                              unsigned short* __restrict__ Kb,
                                              unsigned short* __restrict__ Vb) {
  __shared__ __attribute__((aligned(16))) unsigned short As[3][128 * 32];
  __shared__ __attribute__((aligned(16))) unsigned short Bs[3][128 * 32];
  const int t = threadIdx.x;
  const int jj = blockIdx.x >> 3;
  const int brow = ((blockIdx.x & 7) * 8 + (jj & 7)) * 128;  // 8-M-tile band per XCD
  const int bcol = (jj >> 3) * 128;
  const int lane = t & 63, wid = t >> 6;
  const int wr = (wid >> 1) * 64, wc = (wid & 1) * 64;
  const int g = lane >> 4, qr = lane & 15;
  const f32x4 fzero = {0.f, 0.f, 0.f, 0.f};
  f32x4 acc[4][4];
#pragma unroll
  for (int i = 0; i < 4; ++i)
#pragma unroll
    for (int n = 0; n < 4; ++n) acc[i][n] = fzero;
  const int srow = t >> 2;                 // 0..63
  const int sg = (t & 3) ^ (srow & 3);     // pre-swizzled source chunk
  const unsigned short* Ag0 = A + (size_t)(brow + srow) * 1024 + sg * 8;
  const unsigned short* Bg0 = Bt + (size_t)(bcol + srow) * 1024 + sg * 8;

#define STAGE(s_, kt_)                                        \
  do {                                                        \
    const int koff = (kt_) * 32;                              \
    gl_lds16(Ag0 + koff, &As[s_][t * 8]);                     \
    gl_lds16(Ag0 + 64 * 1024 + koff, &As[s_][2048 + t * 8]);  \
    gl_lds16(Bg0 + koff, &Bs[s_][t * 8]);                     \
    gl_lds16(Bg0 + 64 * 1024 + koff, &Bs[s_][2048 + t * 8]);  \
  } while (0)

  STAGE(0, 0);
  STAGE(1, 1);
  for (int kt = 0; kt < 32; ++kt) {
    const int s = kt % 3;
    if (kt < 31) {
      asm volatile("s_waitcnt vmcnt(4)" ::: "memory");
    } else {
      asm volatile("s_waitcnt vmcnt(0)" ::: "memory");
    }
    __builtin_amdgcn_s_barrier();
    __builtin_amdgcn_sched_barrier(0);
    bf16x8 a[4], b[4];
#pragma unroll
    for (int i = 0; i < 4; ++i) {
      const int r = wr + i * 16 + qr;
      a[i] = *(const bf16x8*)&As[s][r * 32 + ((g ^ (r & 3)) << 3)];
    }
#pragma unroll
    for (int n = 0; n < 4; ++n) {
      const int r = wc + n * 16 + qr;
      b[n] = *(const bf16x8*)&Bs[s][r * 32 + ((g ^ (r & 3)) << 3)];
    }
    __builtin_amdgcn_s_setprio(1);
#pragma unroll
    for (int i = 0; i < 4; ++i)
#pragma unroll
      for (int n = 0; n < 4; ++n)
        acc[i][n] = __builtin_amdgcn_mfma_f32_16x16x32_bf16(a[i], b[n], acc[i][n], 0, 0, 0);
    __builtin_amdgcn_s_setprio(0);
    if (kt < 30) STAGE((kt + 2) % 3, kt + 2);
  }
#undef STAGE
#pragma unroll
  for (int i = 0; i < 4; ++i) {
#pragma unroll
    for (int n = 0; n < 4; ++n) {
      const int col = bcol + wc + n * 16 + qr;
      const float bv = bias[col];
      float v4[4];
#pragma unroll
      for (int r = 0; r < 4; ++r) v4[r] = acc[i][n][r] + bv;
      const int row0 = brow + wr + i * 16 + g * 4;
      if constexpr (EPI == 0) {
#pragma unroll
        for (int r = 0; r < 4; ++r) outF[(size_t)(row0 + r) * Nx + col] = v4[r];
      } else {
        const int bb = row0 >> 11, tkn0 = row0 & 2047;
        const unsigned c = (unsigned)col;
        const unsigned h = c / 192u;
        const unsigned rem = c - h * 192u;
        const unsigned which = rem >> 6, d = rem & 63u;
        if (which == 2u) {  // V transposed [bh][d][tkn]: 4 consecutive tokens -> 8B store
          u16x4 pk;
#pragma unroll
          for (int r = 0; r < 4; ++r) pk[r] = f2bf(v4[r]);
          *(u16x4*)&Vb[(size_t)(((unsigned)bb * 16u + h) * 64u + d) * 2048u + (unsigned)tkn0] = pk;
        } else {
          // Q gets extra log2e fold (softmax computed in exp2 domain)
          const float sc = (which == 0u) ? (0.35355339059327373f * 1.4426950408889634f)
                                         : 0.35355339059327373f;
          unsigned short* dst = (which == 0u) ? Qb : Kb;
#pragma unroll
          for (int r = 0; r < 4; ++r)
            dst[(size_t)(((unsigned)bb * 16u + h) * 2048u + (unsigned)(tkn0 + r)) * 64u + d] =
                f2bf(v4[r] * sc);
        }
      }
    }
  }
}

// -------- flash attention: 8 waves x 32 q-rows (2 groups), KVBLK=64 --------
// R14 kernel with ONE change: Pl row stride 72 -> 76 shorts (152B).  Old stride's
// write banks (4q+8kf+2g mod 32) alias q/q+8 -> 4-way conflict (the 6.29M
// SQ_LDS_BANK_CONFLICT).  New stride: banks 6q+8kf+2g -> 2-way max (free).
__global__ __launch_bounds__(512, 4) void k_attn(const unsigned short* __restrict__ Qb,
                                                 const unsigned short* __restrict__ Kb,
                                                 const unsigned short* __restrict__ Vt,
                                                 unsigned short* __restrict__ Ao) {
  __shared__ __attribute__((aligned(16))) unsigned short Kl[3][64][64];
  __shared__ __attribute__((aligned(16))) unsigned short Vl[2][64][64];
  __shared__ __attribute__((aligned(16))) unsigned short Pl[8][2][16][76];
  const int bid = blockIdx.x;
  const int bh = (bid & 7) * 8 + ((bid >> 3) & 7);  // XCD x owns bh 8x..8x+7 (K/V fits its L2)
  const int qt = bid >> 6;                          // 8 q-tiles of 256 rows
  const int t = threadIdx.x, lane = t & 63, w = t >> 6;  // 8 waves
  const int g = lane >> 4, q = lane & 15;
  const int q0 = qt * 256 + w * 32;
  const unsigned short* Qbase = Qb + ((size_t)bh * 2048 + q0) * 64;
  const char* Kg = (const char*)(Kb + (size_t)bh * 2048 * 64);
  const char* Vg = (const char*)(Vt + (size_t)bh * 64 * 2048);
  const int lr = lane >> 3, lc = lane & 7;
  const int swz = (lc ^ lr) << 4;
  const char* Ksrc = Kg + (size_t)(8 * w + lr) * 128 + swz;
  const char* Vsrc = Vg + (size_t)(8 * w + lr) * 4096 + swz;

#define KST(s_, it_) gl_lds16(Ksrc + (size_t)(it_) * 8192, &Kl[s_][8 * w][0] + lane * 8)
#define VST(b_, it_) gl_lds16(Vsrc + (size_t)(it_) * 128, &Vl[b_][8 * w][0] + lane * 8)

  bf16x8 qf[2][2];
#pragma unroll
  for (int G = 0; G < 2; ++G)
#pragma unroll
    for (int h = 0; h < 2; ++h)
      qf[G][h] = *(const bf16x8*)(Qbase + (size_t)(G * 16 + q) * 64 + h * 32 + g * 8);
  const f32x4 fzero = {0.f, 0.f, 0.f, 0.f};
  f32x4 o0[4], o1[4];
#pragma unroll
  for (int i = 0; i < 4; ++i) { o0[i] = fzero; o1[i] = fzero; }
  float l0 = 0.f, l1 = 0.f;  // lane-partial softmax denominators

  // prologue: K0, V0, K1 (oldest-first order matches per-iter vmcnt(1) wait)
  KST(0, 0);
  VST(0, 0);
  KST(1, 1);

  for (int it = 0; it < 32; ++it) {
    const int s = it % 3, vb = it & 1;
    if (it < 31) {
      asm volatile("s_waitcnt vmcnt(1)" ::: "memory");  // K(it),V(it) landed; next may fly
    } else {
      asm volatile("s_waitcnt vmcnt(0)" ::: "memory");
    }
    __builtin_amdgcn_s_barrier();
    __builtin_amdgcn_sched_barrier(0);
    // ---- QK^T (swapped: A=K rows=keys, B=Q cols=queries), both groups ----
    f32x4 s0[4], s1[4];
    __builtin_amdgcn_s_setprio(1);
#pragma unroll
    for (int kf = 0; kf < 4; ++kf) {
      const int row = kf * 16 + q;
      const char* kp = (const char*)&Kl[s][row][0];
      const int sw = (row & 7) << 4;
      bf16x8 kaL = *(const bf16x8*)(kp + ((g * 16) ^ sw));
      bf16x8 kaH = *(const bf16x8*)(kp + ((64 + g * 16) ^ sw));
      s0[kf] = __builtin_amdgcn_mfma_f32_16x16x32_bf16(kaL, qf[0][0], fzero, 0, 0, 0);
      s0[kf] = __builtin_amdgcn_mfma_f32_16x16x32_bf16(kaH, qf[0][1], s0[kf], 0, 0, 0);
      s1[kf] = __builtin_amdgcn_mfma_f32_16x16x32_bf16(kaL, qf[1][0], fzero, 0, 0, 0);
      s1[kf] = __builtin_amdgcn_mfma_f32_16x16x32_bf16(kaH, qf[1][1], s1[kf], 0, 0, 0);
    }
    __builtin_amdgcn_s_setprio(0);
    // ---- softmax numerators: P = exp2(S), lane-partial l accumulation ----
    {
      unsigned short* Pw = &Pl[w][0][q][0];
#pragma unroll
      for (int kf = 0; kf < 4; ++kf) {
        const float e0 = __builtin_amdgcn_exp2f(s0[kf][0]);
        const float e1 = __builtin_amdgcn_exp2f(s0[kf][1]);
        const float e2 = __builtin_amdgcn_exp2f(s0[kf][2]);
        const float e3 = __builtin_amdgcn_exp2f(s0[kf][3]);
        l0 += (e0 + e1) + (e2 + e3);
        u32x2 pk;
        pk[0] = cvt_pk_bf16(e0, e1);
        pk[1] = cvt_pk_bf16(e2, e3);
        *(u32x2*)(Pw + (8 * kf + 2 * g) * 2) = pk;
      }
    }
    {
      unsigned short* Pw = &Pl[w][1][q][0];
#pragma unroll
      for (int kf = 0; kf < 4; ++kf) {
        const float e0 = __builtin_amdgcn_exp2f(s1[kf][0]);
        const float e1 = __builtin_amdgcn_exp2f(s1[kf][1]);
        const float e2 = __builtin_amdgcn_exp2f(s1[kf][2]);
        const float e3 = __builtin_amdgcn_exp2f(s1[kf][3]);
        l1 += (e0 + e1) + (e2 + e3);
        u32x2 pk;
        pk[0] = cvt_pk_bf16(e0, e1);
        pk[1] = cvt_pk_bf16(e2, e3);
        *(u32x2*)(Pw + (8 * kf + 2 * g) * 2) = pk;
      }
    }
    asm volatile("" ::: "memory");
    // ---- PV, O^T accumulation: D[row=d][col=query] (query lane-local) ----
    const bf16x8 pa00 = *(const bf16x8*)&Pl[w][0][q][g * 8];
    const bf16x8 pa01 = *(const bf16x8*)&Pl[w][0][q][32 + g * 8];
    const bf16x8 pa10 = *(const bf16x8*)&Pl[w][1][q][g * 8];
    const bf16x8 pa11 = *(const bf16x8*)&Pl[w][1][q][32 + g * 8];
    __builtin_amdgcn_s_setprio(1);
#pragma unroll
    for (int dblk = 0; dblk < 4; ++dblk) {
      const int row = dblk * 16 + q;
      const char* vp = (const char*)&Vl[vb][row][0];
      const int sw = (row & 7) << 4;
      bf16x8 vL = *(const bf16x8*)(vp + ((g * 16) ^ sw));
      bf16x8 vH = *(const bf16x8*)(vp + ((64 + g * 16) ^ sw));
      o0[dblk] = __builtin_amdgcn_mfma_f32_16x16x32_bf16(vL, pa00, o0[dblk], 0, 0, 0);
      o0[dblk] = __builtin_amdgcn_mfma_f32_16x16x32_bf16(vH, pa01, o0[dblk], 0, 0, 0);
      o1[dblk] = __builtin_amdgcn_mfma_f32_16x16x32_bf16(vL, pa10, o1[dblk], 0, 0, 0);
      o1[dblk] = __builtin_amdgcn_mfma_f32_16x16x32_bf16(vH, pa11, o1[dblk], 0, 0, 0);
    }
    __builtin_amdgcn_s_setprio(0);
    // ---- issue future stages (V first so needed tiles stay oldest in FIFO) ----
    if (it < 31) VST(vb ^ 1, it + 1);
    if (it < 30) KST((it + 2) % 3, it + 2);
  }
#undef KST
#undef VST
  // finalize l (one cross-lane reduce over g), normalize, write O^T
  l0 += __shfl_xor(l0, 16); l0 += __shfl_xor(l0, 32);
  l1 += __shfl_xor(l1, 16); l1 += __shfl_xor(l1, 32);
  const float li0 = 1.0f / l0, li1 = 1.0f / l1;
  const int bb = bh >> 4, hh = bh & 15;
  {
    unsigned short* ob = Ao + ((size_t)bb * 2048 + q0 + q) * 1024 + hh * 64 + 4 * g;
#pragma unroll
    for (int dblk = 0; dblk < 4; ++dblk) {
      u16x4 pk;
#pragma unroll
      for (int r = 0; r < 4; ++r) pk[r] = f2bf(o0[dblk][r] * li0);
      *(u16x4*)(ob + dblk * 16) = pk;
    }
  }
  {
    unsigned short* ob = Ao + ((size_t)bb * 2048 + q0 + 16 + q) * 1024 + hh * 64 + 4 * g;
#pragma unroll
    for (int dblk = 0; dblk < 4; ++dblk) {
      u16x4 pk;
#pragma unroll
      for (int r = 0; r < 4; ++r) pk[r] = f2bf(o1[dblk][r] * li1);
      *(u16x4*)(ob + dblk * 16) = pk;
    }
  }
}

extern "C" void kernel_launch(void* const* d_in, const int* in_sizes, int n_in,
                              void* d_out, int out_size, void* d_ws, size_t ws_size,
                              hipStream_t stream) {
  const float* x = (const float*)d_in[0];
  const float* w_qkv = (const float*)d_in[1];
  const float* b_qkv = (const float*)d_in[2];
  const float* w_proj = (const float*)d_in[3];
  const float* b_proj = (const float*)d_in[4];
  float* out = (float*)d_out;
  char* ws = (char*)d_ws;
  unsigned short* xb = (unsigned short*)(ws);                  // 16 MB  [8192,1024] bf16
  unsigned short* wqkvT = (unsigned short*)(ws + 16777216);    // 6 MB   [3072,1024]
  unsigned short* wprojT = (unsigned short*)(ws + 23068672);   // 2 MB   [1024,1024]
  unsigned short* Qb = (unsigned short*)(ws + 25165824);       // 16 MB  [bh][2048][64] (log2e folded)
  unsigned short* Kb = (unsigned short*)(ws + 41943040);       // 16 MB  [bh][2048][64]
  unsigned short* Vt = (unsigned short*)(ws + 58720256);       // 16 MB  [bh][64][2048]
  unsigned short* Ao = xb;  // reuse (xb dead after GEMM1)

  hipLaunchKernelGGL(k_prep, dim3(8192), dim3(256), 0, stream,
                     x, xb, w_qkv, wqkvT, w_proj, wprojT);
  hipLaunchKernelGGL((k_gemm<1>), dim3(1536), dim3(256), 0, stream,
                     xb, wqkvT, b_qkv, 3072, (float*)nullptr, Qb, Kb, Vt);
  hipLaunchKernelGGL(k_attn, dim3(512), dim3(512), 0, stream, Qb, Kb, Vt, Ao);
  hipLaunchKernelGGL((k_gemm<0>), dim3(512), dim3(256), 0, stream,
                     Ao, wprojT, b_proj, 1024, out,
                     (unsigned short*)nullptr, (unsigned short*)nullptr, (unsigned short*)nullptr);
}

// Round 17
// 177.942 us; speedup vs baseline: 1.0078x; 1.0078x over previous
//
#include <hip/hip_runtime.h>

typedef __attribute__((ext_vector_type(8))) short bf16x8;   // MFMA A/B frag (8 bf16)
typedef __attribute__((ext_vector_type(4))) float f32x4;    // MFMA C/D frag
typedef __attribute__((ext_vector_type(8))) unsigned short u16x8;
typedef __attribute__((ext_vector_type(4))) unsigned short u16x4;
typedef __attribute__((ext_vector_type(2))) unsigned u32x2;

__device__ __forceinline__ unsigned short f2bf(float f) {
  unsigned u = __builtin_bit_cast(unsigned, f);
  return (unsigned short)((u + 0x7fffu + ((u >> 16) & 1u)) >> 16);
}

__device__ __forceinline__ unsigned cvt_pk_bf16(float lo, float hi) {
  unsigned r;
  asm("v_cvt_pk_bf16_f32 %0, %1, %2" : "=v"(r) : "v"(lo), "v"(hi));
  return r;
}

__device__ __forceinline__ void gl_lds16(const void* g, void* l) {
  __builtin_amdgcn_global_load_lds((const __attribute__((address_space(1))) unsigned*)g,
                                   (__attribute__((address_space(3))) unsigned*)l, 16, 0, 0);
}

// ---------------- merged prep: x->bf16 convert + both weight transposes ----------------
__global__ __launch_bounds__(256) void k_prep(const float* __restrict__ x,
                                              unsigned short* __restrict__ xb,
                                              const float* __restrict__ wq,
                                              unsigned short* __restrict__ wqT,
                                              const float* __restrict__ wp,
                                              unsigned short* __restrict__ wpT) {
  __shared__ float tile[32][33];
  const int bx = blockIdx.x;
  const int t = threadIdx.x;
  if (bx < 4096) {  // convert x fp32 -> bf16, 8 elems/thread
    const int i = bx * 256 + t;
    const float4* s = (const float4*)x;
    float4 a = s[2 * i], b = s[2 * i + 1];
    u16x8 o;
    o[0] = f2bf(a.x); o[1] = f2bf(a.y); o[2] = f2bf(a.z); o[3] = f2bf(a.w);
    o[4] = f2bf(b.x); o[5] = f2bf(b.y); o[6] = f2bf(b.z); o[7] = f2bf(b.w);
    *(u16x8*)(xb + 8 * (size_t)i) = o;
    return;
  }
  // weight transpose+convert [K][N] f32 -> [N][K] bf16
  const int b = bx - 4096;
  const float* w;
  unsigned short* wT;
  int Nn, bb;
  if (b < 3072) { w = wq; wT = wqT; Nn = 3072; bb = b; }
  else          { w = wp; wT = wpT; Nn = 1024; bb = b - 3072; }
  const int k0 = (bb & 31) * 32, n0 = (bb >> 5) * 32;
  const int i = t >> 3, j = (t & 7) * 4;
  float4 v = *(const float4*)(w + (size_t)(k0 + i) * Nn + n0 + j);
  tile[i][j] = v.x; tile[i][j + 1] = v.y; tile[i][j + 2] = v.z; tile[i][j + 3] = v.w;
  __syncthreads();
  const int n = i, k4 = j;
  u16x4 o;
  o[0] = f2bf(tile[k4 + 0][n]); o[1] = f2bf(tile[k4 + 1][n]);
  o[2] = f2bf(tile[k4 + 2][n]); o[3] = f2bf(tile[k4 + 3][n]);
  *(u16x4*)(wT + (size_t)(n0 + n) * 1024 + k0 + k4) = o;
}

// ---------------- GEMM: C[M,Nx] = A[M,1024] @ Bt[Nx,1024]^T + bias ----------------
// 128x128 tile, BK=32, 3-slot LDS ring, counted vmcnt(4), row-XOR swizzle,
// XCD band map (each XCD owns an 8-M-tile band x all N).  (Round-12 verified.)
// EPI 0: fp32 row-major out.  EPI 1: scatter to Q/K bf16 (scaled) + V transposed.
template <int EPI>
__global__ __launch_bounds__(256) void k_gemm(const unsigned short* __restrict__ A,
                                              const unsigned short* __restrict__ Bt,
                                              const float* __restrict__ bias, int Nx,
                                              float* __restrict__ outF,
                                              unsigned short* __restrict__ Qb,
                                              unsigned short* __restrict__ Kb,
                                              unsigned short* __restrict__ Vb) {
  __shared__ __attribute__((aligned(16))) unsigned short As[3][128 * 32];
  __shared__ __attribute__((aligned(16))) unsigned short Bs[3][128 * 32];
  const int t = threadIdx.x;
  const int jj = blockIdx.x >> 3;
  const int brow = ((blockIdx.x & 7) * 8 + (jj & 7)) * 128;  // 8-M-tile band per XCD
  const int bcol = (jj >> 3) * 128;
  const int lane = t & 63, wid = t >> 6;
  const int wr = (wid >> 1) * 64, wc = (wid & 1) * 64;
  const int g = lane >> 4, qr = lane & 15;
  const f32x4 fzero = {0.f, 0.f, 0.f, 0.f};
  f32x4 acc[4][4];
#pragma unroll
  for (int i = 0; i < 4; ++i)
#pragma unroll
    for (int n = 0; n < 4; ++n) acc[i][n] = fzero;
  const int srow = t >> 2;                 // 0..63
  const int sg = (t & 3) ^ (srow & 3);     // pre-swizzled source chunk
  const unsigned short* Ag0 = A + (size_t)(brow + srow) * 1024 + sg * 8;
  const unsigned short* Bg0 = Bt + (size_t)(bcol + srow) * 1024 + sg * 8;

#define STAGE(s_, kt_)                                        \
  do {                                                        \
    const int koff = (kt_) * 32;                              \
    gl_lds16(Ag0 + koff, &As[s_][t * 8]);                     \
    gl_lds16(Ag0 + 64 * 1024 + koff, &As[s_][2048 + t * 8]);  \
    gl_lds16(Bg0 + koff, &Bs[s_][t * 8]);                     \
    gl_lds16(Bg0 + 64 * 1024 + koff, &Bs[s_][2048 + t * 8]);  \
  } while (0)

  STAGE(0, 0);
  STAGE(1, 1);
  for (int kt = 0; kt < 32; ++kt) {
    const int s = kt % 3;
    if (kt < 31) {
      asm volatile("s_waitcnt vmcnt(4)" ::: "memory");
    } else {
      asm volatile("s_waitcnt vmcnt(0)" ::: "memory");
    }
    __builtin_amdgcn_s_barrier();
    __builtin_amdgcn_sched_barrier(0);
    bf16x8 a[4], b[4];
#pragma unroll
    for (int i = 0; i < 4; ++i) {
      const int r = wr + i * 16 + qr;
      a[i] = *(const bf16x8*)&As[s][r * 32 + ((g ^ (r & 3)) << 3)];
    }
#pragma unroll
    for (int n = 0; n < 4; ++n) {
      const int r = wc + n * 16 + qr;
      b[n] = *(const bf16x8*)&Bs[s][r * 32 + ((g ^ (r & 3)) << 3)];
    }
    __builtin_amdgcn_s_setprio(1);
#pragma unroll
    for (int i = 0; i < 4; ++i)
#pragma unroll
      for (int n = 0; n < 4; ++n)
        acc[i][n] = __builtin_amdgcn_mfma_f32_16x16x32_bf16(a[i], b[n], acc[i][n], 0, 0, 0);
    __builtin_amdgcn_s_setprio(0);
    if (kt < 30) STAGE((kt + 2) % 3, kt + 2);
  }
#undef STAGE
#pragma unroll
  for (int i = 0; i < 4; ++i) {
#pragma unroll
    for (int n = 0; n < 4; ++n) {
      const int col = bcol + wc + n * 16 + qr;
      const float bv = bias[col];
      float v4[4];
#pragma unroll
      for (int r = 0; r < 4; ++r) v4[r] = acc[i][n][r] + bv;
      const int row0 = brow + wr + i * 16 + g * 4;
      if constexpr (EPI == 0) {
#pragma unroll
        for (int r = 0; r < 4; ++r) outF[(size_t)(row0 + r) * Nx + col] = v4[r];
      } else {
        const int bb = row0 >> 11, tkn0 = row0 & 2047;
        const unsigned c = (unsigned)col;
        const unsigned h = c / 192u;
        const unsigned rem = c - h * 192u;
        const unsigned which = rem >> 6, d = rem & 63u;
        if (which == 2u) {  // V transposed [bh][d][tkn]: 4 consecutive tokens -> 8B store
          u16x4 pk;
#pragma unroll
          for (int r = 0; r < 4; ++r) pk[r] = f2bf(v4[r]);
          *(u16x4*)&Vb[(size_t)(((unsigned)bb * 16u + h) * 64u + d) * 2048u + (unsigned)tkn0] = pk;
        } else {
          // Q gets extra log2e fold (softmax computed in exp2 domain)
          const float sc = (which == 0u) ? (0.35355339059327373f * 1.4426950408889634f)
                                         : 0.35355339059327373f;
          unsigned short* dst = (which == 0u) ? Qb : Kb;
#pragma unroll
          for (int r = 0; r < 4; ++r)
            dst[(size_t)(((unsigned)bb * 16u + h) * 2048u + (unsigned)(tkn0 + r)) * 64u + d] =
                f2bf(v4[r] * sc);
        }
      }
    }
  }
}

// -------- flash attention: 8 waves x 32 q-rows (2 groups), KVBLK=64 --------
// Round-15 verified kernel, restored byte-identical: counted-vmcnt ring (K 3-slot,
// V dbuf), conflict-free Pl stride 76, no-max exp2 softmax, O^T accum.
__global__ __launch_bounds__(512, 4) void k_attn(const unsigned short* __restrict__ Qb,
                                                 const unsigned short* __restrict__ Kb,
                                                 const unsigned short* __restrict__ Vt,
                                                 unsigned short* __restrict__ Ao) {
  __shared__ __attribute__((aligned(16))) unsigned short Kl[3][64][64];
  __shared__ __attribute__((aligned(16))) unsigned short Vl[2][64][64];
  __shared__ __attribute__((aligned(16))) unsigned short Pl[8][2][16][76];
  const int bid = blockIdx.x;
  const int bh = (bid & 7) * 8 + ((bid >> 3) & 7);  // XCD x owns bh 8x..8x+7 (K/V fits its L2)
  const int qt = bid >> 6;                          // 8 q-tiles of 256 rows
  const int t = threadIdx.x, lane = t & 63, w = t >> 6;  // 8 waves
  const int g = lane >> 4, q = lane & 15;
  const int q0 = qt * 256 + w * 32;
  const unsigned short* Qbase = Qb + ((size_t)bh * 2048 + q0) * 64;
  const char* Kg = (const char*)(Kb + (size_t)bh * 2048 * 64);
  const char* Vg = (const char*)(Vt + (size_t)bh * 64 * 2048);
  const int lr = lane >> 3, lc = lane & 7;
  const int swz = (lc ^ lr) << 4;
  const char* Ksrc = Kg + (size_t)(8 * w + lr) * 128 + swz;
  const char* Vsrc = Vg + (size_t)(8 * w + lr) * 4096 + swz;

#define KST(s_, it_) gl_lds16(Ksrc + (size_t)(it_) * 8192, &Kl[s_][8 * w][0] + lane * 8)
#define VST(b_, it_) gl_lds16(Vsrc + (size_t)(it_) * 128, &Vl[b_][8 * w][0] + lane * 8)

  bf16x8 qf[2][2];
#pragma unroll
  for (int G = 0; G < 2; ++G)
#pragma unroll
    for (int h = 0; h < 2; ++h)
      qf[G][h] = *(const bf16x8*)(Qbase + (size_t)(G * 16 + q) * 64 + h * 32 + g * 8);
  const f32x4 fzero = {0.f, 0.f, 0.f, 0.f};
  f32x4 o0[4], o1[4];
#pragma unroll
  for (int i = 0; i < 4; ++i) { o0[i] = fzero; o1[i] = fzero; }
  float l0 = 0.f, l1 = 0.f;  // lane-partial softmax denominators

  // prologue: K0, V0, K1 (oldest-first order matches per-iter vmcnt(1) wait)
  KST(0, 0);
  VST(0, 0);
  KST(1, 1);

  for (int it = 0; it < 32; ++it) {
    const int s = it % 3, vb = it & 1;
    if (it < 31) {
      asm volatile("s_waitcnt vmcnt(1)" ::: "memory");  // K(it),V(it) landed; next may fly
    } else {
      asm volatile("s_waitcnt vmcnt(0)" ::: "memory");
    }
    __builtin_amdgcn_s_barrier();
    __builtin_amdgcn_sched_barrier(0);
    // ---- QK^T (swapped: A=K rows=keys, B=Q cols=queries), both groups ----
    f32x4 s0[4], s1[4];
    __builtin_amdgcn_s_setprio(1);
#pragma unroll
    for (int kf = 0; kf < 4; ++kf) {
      const int row = kf * 16 + q;
      const char* kp = (const char*)&Kl[s][row][0];
      const int sw = (row & 7) << 4;
      bf16x8 kaL = *(const bf16x8*)(kp + ((g * 16) ^ sw));
      bf16x8 kaH = *(const bf16x8*)(kp + ((64 + g * 16) ^ sw));
      s0[kf] = __builtin_amdgcn_mfma_f32_16x16x32_bf16(kaL, qf[0][0], fzero, 0, 0, 0);
      s0[kf] = __builtin_amdgcn_mfma_f32_16x16x32_bf16(kaH, qf[0][1], s0[kf], 0, 0, 0);
      s1[kf] = __builtin_amdgcn_mfma_f32_16x16x32_bf16(kaL, qf[1][0], fzero, 0, 0, 0);
      s1[kf] = __builtin_amdgcn_mfma_f32_16x16x32_bf16(kaH, qf[1][1], s1[kf], 0, 0, 0);
    }
    __builtin_amdgcn_s_setprio(0);
    // ---- softmax numerators: P = exp2(S), lane-partial l accumulation ----
    {
      unsigned short* Pw = &Pl[w][0][q][0];
#pragma unroll
      for (int kf = 0; kf < 4; ++kf) {
        const float e0 = __builtin_amdgcn_exp2f(s0[kf][0]);
        const float e1 = __builtin_amdgcn_exp2f(s0[kf][1]);
        const float e2 = __builtin_amdgcn_exp2f(s0[kf][2]);
        const float e3 = __builtin_amdgcn_exp2f(s0[kf][3]);
        l0 += (e0 + e1) + (e2 + e3);
        u32x2 pk;
        pk[0] = cvt_pk_bf16(e0, e1);
        pk[1] = cvt_pk_bf16(e2, e3);
        *(u32x2*)(Pw + (8 * kf + 2 * g) * 2) = pk;
      }
    }
    {
      unsigned short* Pw = &Pl[w][1][q][0];
#pragma unroll
      for (int kf = 0; kf < 4; ++kf) {
        const float e0 = __builtin_amdgcn_exp2f(s1[kf][0]);
        const float e1 = __builtin_amdgcn_exp2f(s1[kf][1]);
        const float e2 = __builtin_amdgcn_exp2f(s1[kf][2]);
        const float e3 = __builtin_amdgcn_exp2f(s1[kf][3]);
        l1 += (e0 + e1) + (e2 + e3);
        u32x2 pk;
        pk[0] = cvt_pk_bf16(e0, e1);
        pk[1] = cvt_pk_bf16(e2, e3);
        *(u32x2*)(Pw + (8 * kf + 2 * g) * 2) = pk;
      }
    }
    asm volatile("" ::: "memory");
    // ---- PV, O^T accumulation: D[row=d][col=query] (query lane-local) ----
    const bf16x8 pa00 = *(const bf16x8*)&Pl[w][0][q][g * 8];
    const bf16x8 pa01 = *(const bf16x8*)&Pl[w][0][q][32 + g * 8];
    const bf16x8 pa10 = *(const bf16x8*)&Pl[w][1][q][g * 8];
    const bf16x8 pa11 = *(const bf16x8*)&Pl[w][1][q][32 + g * 8];
    __builtin_amdgcn_s_setprio(1);
#pragma unroll
    for (int dblk = 0; dblk < 4; ++dblk) {
      const int row = dblk * 16 + q;
      const char* vp = (const char*)&Vl[vb][row][0];
      const int sw = (row & 7) << 4;
      bf16x8 vL = *(const bf16x8*)(vp + ((g * 16) ^ sw));
      bf16x8 vH = *(const bf16x8*)(vp + ((64 + g * 16) ^ sw));
      o0[dblk] = __builtin_amdgcn_mfma_f32_16x16x32_bf16(vL, pa00, o0[dblk], 0, 0, 0);
      o0[dblk] = __builtin_amdgcn_mfma_f32_16x16x32_bf16(vH, pa01, o0[dblk], 0, 0, 0);
      o1[dblk] = __builtin_amdgcn_mfma_f32_16x16x32_bf16(vL, pa10, o1[dblk], 0, 0, 0);
      o1[dblk] = __builtin_amdgcn_mfma_f32_16x16x32_bf16(vH, pa11, o1[dblk], 0, 0, 0);
    }
    __builtin_amdgcn_s_setprio(0);
    // ---- issue future stages (V first so needed tiles stay oldest in FIFO) ----
    if (it < 31) VST(vb ^ 1, it + 1);
    if (it < 30) KST((it + 2) % 3, it + 2);
  }
#undef KST
#undef VST
  // finalize l (one cross-lane reduce over g), normalize, write O^T
  l0 += __shfl_xor(l0, 16); l0 += __shfl_xor(l0, 32);
  l1 += __shfl_xor(l1, 16); l1 += __shfl_xor(l1, 32);
  const float li0 = 1.0f / l0, li1 = 1.0f / l1;
  const int bb = bh >> 4, hh = bh & 15;
  {
    unsigned short* ob = Ao + ((size_t)bb * 2048 + q0 + q) * 1024 + hh * 64 + 4 * g;
#pragma unroll
    for (int dblk = 0; dblk < 4; ++dblk) {
      u16x4 pk;
#pragma unroll
      for (int r = 0; r < 4; ++r) pk[r] = f2bf(o0[dblk][r] * li0);
      *(u16x4*)(ob + dblk * 16) = pk;
    }
  }
  {
    unsigned short* ob = Ao + ((size_t)bb * 2048 + q0 + 16 + q) * 1024 + hh * 64 + 4 * g;
#pragma unroll
    for (int dblk = 0; dblk < 4; ++dblk) {
      u16x4 pk;
#pragma unroll
      for (int r = 0; r < 4; ++r) pk[r] = f2bf(o1[dblk][r] * li1);
      *(u16x4*)(ob + dblk * 16) = pk;
    }
  }
}

extern "C" void kernel_launch(void* const* d_in, const int* in_sizes, int n_in,
                              void* d_out, int out_size, void* d_ws, size_t ws_size,
                              hipStream_t stream) {
  const float* x = (const float*)d_in[0];
  const float* w_qkv = (const float*)d_in[1];
  const float* b_qkv = (const float*)d_in[2];
  const float* w_proj = (const float*)d_in[3];
  const float* b_proj = (const float*)d_in[4];
  float* out = (float*)d_out;
  char* ws = (char*)d_ws;
  unsigned short* xb = (unsigned short*)(ws);                  // 16 MB  [8192,1024] bf16
  unsigned short* wqkvT = (unsigned short*)(ws + 16777216);    // 6 MB   [3072,1024]
  unsigned short* wprojT = (unsigned short*)(ws + 23068672);   // 2 MB   [1024,1024]
  unsigned short* Qb = (unsigned short*)(ws + 25165824);       // 16 MB  [bh][2048][64] (log2e folded)
  unsigned short* Kb = (unsigned short*)(ws + 41943040);       // 16 MB  [bh][2048][64]
  unsigned short* Vt = (unsigned short*)(ws + 58720256);       // 16 MB  [bh][64][2048]
  unsigned short* Ao = xb;  // reuse (xb dead after GEMM1)

  hipLaunchKernelGGL(k_prep, dim3(8192), dim3(256), 0, stream,
                     x, xb, w_qkv, wqkvT, w_proj, wprojT);
  hipLaunchKernelGGL((k_gemm<1>), dim3(1536), dim3(256), 0, stream,
                     xb, wqkvT, b_qkv, 3072, (float*)nullptr, Qb, Kb, Vt);
  hipLaunchKernelGGL(k_attn, dim3(512), dim3(512), 0, stream, Qb, Kb, Vt, Ao);
  hipLaunchKernelGGL((k_gemm<0>), dim3(512), dim3(256), 0, stream,
                     Ao, wprojT, b_proj, 1024, out,
                     (unsigned short*)nullptr, (unsigned short*)nullptr, (unsigned short*)nullptr);
}